// Round 6
// baseline (366.626 us; speedup 1.0000x reference)
//
#include <hip/hip_runtime.h>

#define KK 5
#define RR 2
#define N_ 2
#define C_ 256
#define H_ 128
#define W_ 128
#define H2 256
#define W2 256
#define TH 16
#define TW 16
#define CCHUNK 8
#define PH 20
#define PW 20
#define PHPW 400
#define HW (H_*W_)
#define HW2 (H2*W2)
#define DEPTH 2              // mask prefetch ring depth

__global__ __launch_bounds__(256, 8) void carafe_kernel(
    const float* __restrict__ feat,
    const float* __restrict__ masks,
    float* __restrict__ out)
{
    // Channel-group-planar: word = G*1600 + p*4 + t holds channel 4G+t at
    // pixel p (G in {0,1}). b128 writes and reads both land 8 words/bank
    // across 64 lanes = the LDS throughput floor.
    __shared__ float patch[2 * PHPW * 4];   // 3200 words = 12800 B

    const int tid = threadIdx.x;
    const int tx = tid & 15;
    const int ty = tid >> 4;
    const int bx = blockIdx.x & 7;     // W_/TW = 8
    const int by = blockIdx.x >> 3;    // H_/TH = 8
    const int c0 = blockIdx.y * CCHUNK;
    const int n  = blockIdx.z;

    const int i0 = by * TH + ty;
    const int j0 = bx * TW + tx;
    const int gy0 = by * TH - RR;
    const int gx0 = bx * TW - RR;

    // ---- stage 8 channels' 20x20 halo patches: 800 float4 slots, 4 rounds ----
    const float* fbase = feat + (size_t)(n * C_ + c0) * HW;
    #pragma unroll
    for (int r = 0; r < 4; ++r) {
        const int idx = tid + r * 256;
        if (idx < 2 * PHPW) {
            const int G  = idx / PHPW;          // 0 or 1
            const int p  = idx - G * PHPW;
            const int py = p / PW;
            const int px = p - py * PW;
            const int gy = gy0 + py;
            const int gx = gx0 + px;
            float4 v = make_float4(0.f, 0.f, 0.f, 0.f);
            if ((unsigned)gy < (unsigned)H_ && (unsigned)gx < (unsigned)W_) {
                const float* fp = fbase + (4 * G) * HW + gy * W_ + gx;
                v.x = fp[0];
                v.y = fp[HW];
                v.z = fp[2 * HW];
                v.w = fp[3 * HW];
            }
            *reinterpret_cast<float4*>(&patch[G * 1600 + p * 4]) = v;
        }
    }

    // ---- mask ring preload (latency hides under staging drain + barrier) ----
    const float* mb = masks + ((size_t)n * (KK * KK) * H2 + (size_t)(2 * i0)) * W2 + 2 * j0;
    float2 q0[DEPTH], q1[DEPTH];
    #pragma unroll
    for (int t = 0; t < DEPTH; ++t) {
        q0[t] = *reinterpret_cast<const float2*>(mb + (size_t)t * HW2);
        q1[t] = *reinterpret_cast<const float2*>(mb + (size_t)t * HW2 + W2);
    }
    __syncthreads();

    // ---- k-outer / channel-inner, depth-2 mask ring ----
    float acc[CCHUNK][2][2] = {};
    const int p0 = ty * PW + tx;

    #pragma unroll
    for (int k = 0; k < KK * KK; ++k) {
        const float2 m0 = q0[k % DEPTH];   // static index after unroll
        const float2 m1 = q1[k % DEPTH];
        if (k + DEPTH < KK * KK) {
            q0[k % DEPTH] = *reinterpret_cast<const float2*>(mb + (size_t)(k + DEPTH) * HW2);
            q1[k % DEPTH] = *reinterpret_cast<const float2*>(mb + (size_t)(k + DEPTH) * HW2 + W2);
        }
        const int dy = k / KK;
        const int dx = k - KK * dy;
        const int P  = p0 + dy * PW + dx;
        const float4 v0 = *reinterpret_cast<const float4*>(&patch[P * 4]);
        const float4 v1 = *reinterpret_cast<const float4*>(&patch[1600 + P * 4]);

        acc[0][0][0] += v0.x * m0.x;  acc[0][0][1] += v0.x * m0.y;
        acc[0][1][0] += v0.x * m1.x;  acc[0][1][1] += v0.x * m1.y;
        acc[1][0][0] += v0.y * m0.x;  acc[1][0][1] += v0.y * m0.y;
        acc[1][1][0] += v0.y * m1.x;  acc[1][1][1] += v0.y * m1.y;
        acc[2][0][0] += v0.z * m0.x;  acc[2][0][1] += v0.z * m0.y;
        acc[2][1][0] += v0.z * m1.x;  acc[2][1][1] += v0.z * m1.y;
        acc[3][0][0] += v0.w * m0.x;  acc[3][0][1] += v0.w * m0.y;
        acc[3][1][0] += v0.w * m1.x;  acc[3][1][1] += v0.w * m1.y;
        acc[4][0][0] += v1.x * m0.x;  acc[4][0][1] += v1.x * m0.y;
        acc[4][1][0] += v1.x * m1.x;  acc[4][1][1] += v1.x * m1.y;
        acc[5][0][0] += v1.y * m0.x;  acc[5][0][1] += v1.y * m0.y;
        acc[5][1][0] += v1.y * m1.x;  acc[5][1][1] += v1.y * m1.y;
        acc[6][0][0] += v1.z * m0.x;  acc[6][0][1] += v1.z * m0.y;
        acc[6][1][0] += v1.z * m1.x;  acc[6][1][1] += v1.z * m1.y;
        acc[7][0][0] += v1.w * m0.x;  acc[7][0][1] += v1.w * m0.y;
        acc[7][1][0] += v1.w * m1.x;  acc[7][1][1] += v1.w * m1.y;
    }

    // ---- store: 8 channels x 2x2 quad, float2 rows ----
    float* ob = out + ((size_t)(n * C_ + c0) * H2 + (size_t)(2 * i0)) * W2 + 2 * j0;
    #pragma unroll
    for (int c = 0; c < CCHUNK; ++c) {
        *reinterpret_cast<float2*>(ob)      = make_float2(acc[c][0][0], acc[c][0][1]);
        *reinterpret_cast<float2*>(ob + W2) = make_float2(acc[c][1][0], acc[c][1][1]);
        ob += (size_t)HW2;
    }
}

extern "C" void kernel_launch(void* const* d_in, const int* in_sizes, int n_in,
                              void* d_out, int out_size, void* d_ws, size_t ws_size,
                              hipStream_t stream) {
    const float* feat  = (const float*)d_in[0];
    const float* masks = (const float*)d_in[1];
    float* out = (float*)d_out;

    dim3 grid((W_ / TW) * (H_ / TH),   // 64 spatial tiles
              C_ / CCHUNK,             // 32 channel chunks
              N_);                     // 2 batch
    carafe_kernel<<<grid, dim3(256), 0, stream>>>(feat, masks, out);
}

// Round 7
// 69.134 us; speedup vs baseline: 5.3032x; 5.3032x over previous
//
#include <hip/hip_runtime.h>

#define KK 5
#define RR 2
#define N_ 2
#define C_ 256
#define H_ 128
#define W_ 128
#define H2 256
#define W2 256
#define TH 16
#define TW 16
#define CCHUNK 8
#define PH 20
#define PW 20
#define PHPW 400
#define HW (H_*W_)
#define HW2 (H2*W2)
#define DEPTH 2              // mask prefetch ring depth

__global__ __launch_bounds__(256) void carafe_kernel(
    const float* __restrict__ feat,
    const float* __restrict__ masks,
    float* __restrict__ out)
{
    // Channel-group-planar: word = G*1600 + p*4 + t holds channel 4G+t at
    // pixel p (G in {0,1}). b128 writes and reads both land 8 words/bank
    // across 64 lanes = the LDS throughput floor.
    __shared__ float patch[2 * PHPW * 4];   // 3200 words = 12800 B

    const int tid = threadIdx.x;
    const int tx = tid & 15;
    const int ty = tid >> 4;
    const int bx = blockIdx.x & 7;     // W_/TW = 8
    const int by = blockIdx.x >> 3;    // H_/TH = 8
    const int c0 = blockIdx.y * CCHUNK;
    const int n  = blockIdx.z >> 1;
    const int a  = blockIdx.z & 1;     // which output subpixel ROW this block computes

    const int i0 = by * TH + ty;
    const int j0 = bx * TW + tx;
    const int gy0 = by * TH - RR;
    const int gx0 = bx * TW - RR;

    // ---- stage 8 channels' 20x20 halo patches: 800 float4 slots, 4 rounds ----
    const float* fbase = feat + (size_t)(n * C_ + c0) * HW;
    #pragma unroll
    for (int r = 0; r < 4; ++r) {
        const int idx = tid + r * 256;
        if (idx < 2 * PHPW) {
            const int G  = idx / PHPW;          // 0 or 1
            const int p  = idx - G * PHPW;
            const int py = p / PW;
            const int px = p - py * PW;
            const int gy = gy0 + py;
            const int gx = gx0 + px;
            float4 v = make_float4(0.f, 0.f, 0.f, 0.f);
            if ((unsigned)gy < (unsigned)H_ && (unsigned)gx < (unsigned)W_) {
                const float* fp = fbase + (4 * G) * HW + gy * W_ + gx;
                v.x = fp[0];
                v.y = fp[HW];
                v.z = fp[2 * HW];
                v.w = fp[3 * HW];
            }
            *reinterpret_cast<float4*>(&patch[G * 1600 + p * 4]) = v;
        }
    }

    // ---- mask ring preload: one float2 per k (this block's output row only) ----
    const float* mb = masks + ((size_t)n * (KK * KK) * H2 + (size_t)(2 * i0 + a)) * W2 + 2 * j0;
    float2 q[DEPTH];
    #pragma unroll
    for (int t = 0; t < DEPTH; ++t)
        q[t] = *reinterpret_cast<const float2*>(mb + (size_t)t * HW2);
    __syncthreads();

    // ---- k-outer / channel-inner, depth-2 mask ring ----
    float acc[CCHUNK][2] = {};
    const int p0 = ty * PW + tx;

    #pragma unroll
    for (int k = 0; k < KK * KK; ++k) {
        const float2 m = q[k % DEPTH];   // static index after unroll
        if (k + DEPTH < KK * KK)
            q[k % DEPTH] = *reinterpret_cast<const float2*>(mb + (size_t)(k + DEPTH) * HW2);
        const int dy = k / KK;
        const int dx = k - KK * dy;
        const int P  = p0 + dy * PW + dx;
        const float4 v0 = *reinterpret_cast<const float4*>(&patch[P * 4]);
        const float4 v1 = *reinterpret_cast<const float4*>(&patch[1600 + P * 4]);

        acc[0][0] += v0.x * m.x;  acc[0][1] += v0.x * m.y;
        acc[1][0] += v0.y * m.x;  acc[1][1] += v0.y * m.y;
        acc[2][0] += v0.z * m.x;  acc[2][1] += v0.z * m.y;
        acc[3][0] += v0.w * m.x;  acc[3][1] += v0.w * m.y;
        acc[4][0] += v1.x * m.x;  acc[4][1] += v1.x * m.y;
        acc[5][0] += v1.y * m.x;  acc[5][1] += v1.y * m.y;
        acc[6][0] += v1.z * m.x;  acc[6][1] += v1.z * m.y;
        acc[7][0] += v1.w * m.x;  acc[7][1] += v1.w * m.y;
    }

    // ---- store: 8 channels x one float2 row ----
    float* ob = out + ((size_t)(n * C_ + c0) * H2 + (size_t)(2 * i0 + a)) * W2 + 2 * j0;
    #pragma unroll
    for (int c = 0; c < CCHUNK; ++c) {
        *reinterpret_cast<float2*>(ob) = make_float2(acc[c][0], acc[c][1]);
        ob += (size_t)HW2;
    }
}

extern "C" void kernel_launch(void* const* d_in, const int* in_sizes, int n_in,
                              void* d_out, int out_size, void* d_ws, size_t ws_size,
                              hipStream_t stream) {
    const float* feat  = (const float*)d_in[0];
    const float* masks = (const float*)d_in[1];
    float* out = (float*)d_out;

    dim3 grid((W_ / TW) * (H_ / TH),   // 64 spatial tiles
              C_ / CCHUNK,             // 32 channel chunks
              N_ * 2);                 // batch x subpixel-row
    carafe_kernel<<<grid, dim3(256), 0, stream>>>(feat, masks, out);
}

// Round 8
// 57.771 us; speedup vs baseline: 6.3462x; 1.1967x over previous
//
#include <hip/hip_runtime.h>

#define KK 5
#define RR 2
#define N_ 2
#define C_ 256
#define H_ 128
#define W_ 128
#define H2 256
#define W2 256
#define TH 16
#define TW 16
#define CCHUNK 8
#define PH 20              // halo rows
#define PWPIX 20           // halo cols (pixels)
#define PSTR 21            // padded row stride in pixels (odd -> uniform bank spread)
#define PLANE (PH*PSTR*4)  // 1680 words per 4-channel plane
#define HW (H_*W_)
#define HW2 (H2*W2)
#define DEPTH 2            // mask prefetch ring depth

__global__ __launch_bounds__(256) void carafe_kernel(
    const float* __restrict__ feat,
    const float* __restrict__ masks,
    float* __restrict__ out)
{
    // Two 4-channel planes; word = q*PLANE + (py*21+px)*4 + t  (channel c0+4q+t).
    // b128 = one pixel x 4 ch. Odd row stride 21 -> p mod 8 uniform across a
    // wave -> 8 words/bank = conflict floor for reads AND stage writes.
    __shared__ float patch[2 * PLANE];   // 3360 words = 13440 B

    const int tid = threadIdx.x;
    const int q   = tid >> 7;          // channel-quad plane (wave-uniform)
    const int pp  = tid & 127;
    const int txp = pp & 7;            // pixel-pair x index: owns pixels 2txp, 2txp+1
    const int ty  = pp >> 3;           // 0..15
    const int bx  = blockIdx.x & 7;
    const int by  = blockIdx.x >> 3;
    const int c0  = blockIdx.y * CCHUNK;
    const int n   = blockIdx.z;

    const int i0 = by * TH + ty;           // source row
    const int j0 = bx * TW + 2 * txp;      // first source col of the pair
    const int gy0 = by * TH - RR;
    const int gx0 = bx * TW - RR;

    // ---- stage: 800 b128 slots (2 planes x 400 pixels), 4 rounds ----
    const float* fbase = feat + (size_t)(n * C_ + c0) * HW;
    #pragma unroll
    for (int r = 0; r < 4; ++r) {
        const int idx = tid + r * 256;
        if (idx < 2 * PH * PWPIX) {
            const int G   = idx >= PH * PWPIX;
            const int pix = idx - G * (PH * PWPIX);
            const int py  = pix / PWPIX;
            const int px  = pix - py * PWPIX;
            const int gy  = gy0 + py;
            const int gx  = gx0 + px;
            float4 v = make_float4(0.f, 0.f, 0.f, 0.f);
            if ((unsigned)gy < (unsigned)H_ && (unsigned)gx < (unsigned)W_) {
                const float* fp = fbase + (4 * G) * HW + gy * W_ + gx;
                v.x = fp[0];
                v.y = fp[HW];
                v.z = fp[2 * HW];
                v.w = fp[3 * HW];
            }
            *reinterpret_cast<float4*>(&patch[G * PLANE + (py * PSTR + px) * 4]) = v;
        }
    }

    // ---- mask ring preload: 2 float4 per k (rows a=0,1; cols 2j0..2j0+3) ----
    const float* mb = masks + ((size_t)n * (KK * KK) * H2 + (size_t)(2 * i0)) * W2 + 2 * j0;
    float4 qr[DEPTH][2];
    #pragma unroll
    for (int t = 0; t < DEPTH; ++t) {
        qr[t][0] = *reinterpret_cast<const float4*>(mb + (size_t)t * HW2);
        qr[t][1] = *reinterpret_cast<const float4*>(mb + (size_t)t * HW2 + W2);
    }
    __syncthreads();

    // ---- dy-outer: read the 6-pixel row span once, reuse across 5 dx ----
    float acc[4][2][2][2] = {};   // [t ch][x pix][a row][b col]
    const int rb0 = q * PLANE + (ty * PSTR + 2 * txp) * 4;

    #pragma unroll
    for (int dy = 0; dy < KK; ++dy) {
        float4 w[6];
        #pragma unroll
        for (int u = 0; u < 6; ++u)
            w[u] = *reinterpret_cast<const float4*>(&patch[rb0 + dy * (PSTR * 4) + u * 4]);

        #pragma unroll
        for (int dx = 0; dx < KK; ++dx) {
            const int k = dy * KK + dx;
            const float4 m0 = qr[k % DEPTH][0];   // row a=0: [pix0.b0, pix0.b1, pix1.b0, pix1.b1]
            const float4 m1 = qr[k % DEPTH][1];   // row a=1
            if (k + DEPTH < KK * KK) {
                qr[k % DEPTH][0] = *reinterpret_cast<const float4*>(mb + (size_t)(k + DEPTH) * HW2);
                qr[k % DEPTH][1] = *reinterpret_cast<const float4*>(mb + (size_t)(k + DEPTH) * HW2 + W2);
            }
            const float4 w0 = w[dx];       // pixel0's window value, 4 ch
            const float4 w1 = w[dx + 1];   // pixel1's
            const float wa0[4] = { w0.x, w0.y, w0.z, w0.w };
            const float wa1[4] = { w1.x, w1.y, w1.z, w1.w };
            #pragma unroll
            for (int t = 0; t < 4; ++t) {
                acc[t][0][0][0] += wa0[t] * m0.x;  acc[t][0][0][1] += wa0[t] * m0.y;
                acc[t][1][0][0] += wa1[t] * m0.z;  acc[t][1][0][1] += wa1[t] * m0.w;
                acc[t][0][1][0] += wa0[t] * m1.x;  acc[t][0][1][1] += wa0[t] * m1.y;
                acc[t][1][1][0] += wa1[t] * m1.z;  acc[t][1][1][1] += wa1[t] * m1.w;
            }
        }
    }

    // ---- store: 4 ch x 2 rows, one float4 (4 output cols) each ----
    #pragma unroll
    for (int t = 0; t < 4; ++t) {
        #pragma unroll
        for (int a = 0; a < 2; ++a) {
            float* ob = out + ((size_t)(n * C_ + c0 + 4 * q + t) * H2 + (size_t)(2 * i0 + a)) * W2 + 2 * j0;
            *reinterpret_cast<float4*>(ob) =
                make_float4(acc[t][0][a][0], acc[t][0][a][1], acc[t][1][a][0], acc[t][1][a][1]);
        }
    }
}

extern "C" void kernel_launch(void* const* d_in, const int* in_sizes, int n_in,
                              void* d_out, int out_size, void* d_ws, size_t ws_size,
                              hipStream_t stream) {
    const float* feat  = (const float*)d_in[0];
    const float* masks = (const float*)d_in[1];
    float* out = (float*)d_out;

    dim3 grid((W_ / TW) * (H_ / TH),   // 64 spatial tiles
              C_ / CCHUNK,             // 32 channel chunks
              N_);                     // 2 batch
    carafe_kernel<<<grid, dim3(256), 0, stream>>>(feat, masks, out);
}

// Round 9
// 52.139 us; speedup vs baseline: 7.0317x; 1.1080x over previous
//
#include <hip/hip_runtime.h>

#define KK 5
#define RR 2
#define N_ 2
#define C_ 256
#define H_ 128
#define W_ 128
#define H2 256
#define W2 256
#define TH 16
#define TW 16
#define CCHUNK 8
#define PH 20
#define PW 20
#define PHPW 400
#define HW (H_*W_)
#define HW2 (H2*W2)
#define DEPTH 4              // mask prefetch ring depth

__global__ __launch_bounds__(256) void carafe_kernel(
    const float* __restrict__ feat,
    const float* __restrict__ masks,
    float* __restrict__ out)
{
    // Channel-group-planar: word = G*1600 + p*4 + t holds channel 4G+t at
    // pixel p (G in {0,1}). b128 writes and reads both land 8 words/bank
    // across 64 lanes = the LDS throughput floor.
    __shared__ float patch[2 * PHPW * 4];   // 3200 words = 12800 B

    const int tid = threadIdx.x;
    const int tx = tid & 15;
    const int ty = tid >> 4;

    // chunk-FASTEST block order: concurrent blocks share one tile's masks
    // (hot in L2) instead of sharing features and thrashing masks in L3.
    const int chunk = blockIdx.x & 31;
    const int tile  = blockIdx.x >> 5;
    const int bx = tile & 7;           // W_/TW = 8
    const int by = tile >> 3;          // H_/TH = 8
    const int c0 = chunk * CCHUNK;
    const int n  = blockIdx.y;

    const int i0 = by * TH + ty;
    const int j0 = bx * TW + tx;
    const int gy0 = by * TH - RR;
    const int gx0 = bx * TW - RR;

    // ---- stage 8 channels' 20x20 halo patches: 800 float4 slots, 4 rounds ----
    const float* fbase = feat + (size_t)(n * C_ + c0) * HW;
    #pragma unroll
    for (int r = 0; r < 4; ++r) {
        const int idx = tid + r * 256;
        if (idx < 2 * PHPW) {
            const int G  = idx / PHPW;          // 0 or 1
            const int p  = idx - G * PHPW;
            const int py = p / PW;
            const int px = p - py * PW;
            const int gy = gy0 + py;
            const int gx = gx0 + px;
            float4 v = make_float4(0.f, 0.f, 0.f, 0.f);
            if ((unsigned)gy < (unsigned)H_ && (unsigned)gx < (unsigned)W_) {
                const float* fp = fbase + (4 * G) * HW + gy * W_ + gx;
                v.x = fp[0];
                v.y = fp[HW];
                v.z = fp[2 * HW];
                v.w = fp[3 * HW];
            }
            *reinterpret_cast<float4*>(&patch[G * 1600 + p * 4]) = v;
        }
    }

    // ---- mask ring preload (latency hides under staging drain + barrier) ----
    const float* mb = masks + ((size_t)n * (KK * KK) * H2 + (size_t)(2 * i0)) * W2 + 2 * j0;
    float2 q0[DEPTH], q1[DEPTH];
    #pragma unroll
    for (int t = 0; t < DEPTH; ++t) {
        q0[t] = *reinterpret_cast<const float2*>(mb + (size_t)t * HW2);
        q1[t] = *reinterpret_cast<const float2*>(mb + (size_t)t * HW2 + W2);
    }
    __syncthreads();

    // ---- k-outer / channel-inner, depth-4 mask ring ----
    float acc[CCHUNK][2][2] = {};
    const int p0 = ty * PW + tx;

    #pragma unroll
    for (int k = 0; k < KK * KK; ++k) {
        const float2 m0 = q0[k % DEPTH];   // static index after unroll
        const float2 m1 = q1[k % DEPTH];
        if (k + DEPTH < KK * KK) {
            q0[k % DEPTH] = *reinterpret_cast<const float2*>(mb + (size_t)(k + DEPTH) * HW2);
            q1[k % DEPTH] = *reinterpret_cast<const float2*>(mb + (size_t)(k + DEPTH) * HW2 + W2);
        }
        const int dy = k / KK;
        const int dx = k - KK * dy;
        const int P  = p0 + dy * PW + dx;
        const float4 v0 = *reinterpret_cast<const float4*>(&patch[P * 4]);
        const float4 v1 = *reinterpret_cast<const float4*>(&patch[1600 + P * 4]);

        acc[0][0][0] += v0.x * m0.x;  acc[0][0][1] += v0.x * m0.y;
        acc[0][1][0] += v0.x * m1.x;  acc[0][1][1] += v0.x * m1.y;
        acc[1][0][0] += v0.y * m0.x;  acc[1][0][1] += v0.y * m0.y;
        acc[1][1][0] += v0.y * m1.x;  acc[1][1][1] += v0.y * m1.y;
        acc[2][0][0] += v0.z * m0.x;  acc[2][0][1] += v0.z * m0.y;
        acc[2][1][0] += v0.z * m1.x;  acc[2][1][1] += v0.z * m1.y;
        acc[3][0][0] += v0.w * m0.x;  acc[3][0][1] += v0.w * m0.y;
        acc[3][1][0] += v0.w * m1.x;  acc[3][1][1] += v0.w * m1.y;
        acc[4][0][0] += v1.x * m0.x;  acc[4][0][1] += v1.x * m0.y;
        acc[4][1][0] += v1.x * m1.x;  acc[4][1][1] += v1.x * m1.y;
        acc[5][0][0] += v1.y * m0.x;  acc[5][0][1] += v1.y * m0.y;
        acc[5][1][0] += v1.y * m1.x;  acc[5][1][1] += v1.y * m1.y;
        acc[6][0][0] += v1.z * m0.x;  acc[6][0][1] += v1.z * m0.y;
        acc[6][1][0] += v1.z * m1.x;  acc[6][1][1] += v1.z * m1.y;
        acc[7][0][0] += v1.w * m0.x;  acc[7][0][1] += v1.w * m0.y;
        acc[7][1][0] += v1.w * m1.x;  acc[7][1][1] += v1.w * m1.y;
    }

    // ---- store: 8 channels x 2x2 quad, float2 rows ----
    float* ob = out + ((size_t)(n * C_ + c0) * H2 + (size_t)(2 * i0)) * W2 + 2 * j0;
    #pragma unroll
    for (int c = 0; c < CCHUNK; ++c) {
        *reinterpret_cast<float2*>(ob)      = make_float2(acc[c][0][0], acc[c][0][1]);
        *reinterpret_cast<float2*>(ob + W2) = make_float2(acc[c][1][0], acc[c][1][1]);
        ob += (size_t)HW2;
    }
}

extern "C" void kernel_launch(void* const* d_in, const int* in_sizes, int n_in,
                              void* d_out, int out_size, void* d_ws, size_t ws_size,
                              hipStream_t stream) {
    const float* feat  = (const float*)d_in[0];
    const float* masks = (const float*)d_in[1];
    float* out = (float*)d_out;

    dim3 grid(32 * 64,   // chunk (fastest, 32) x tile (64)
              N_);       // batch
    carafe_kernel<<<grid, dim3(256), 0, stream>>>(feat, masks, out);
}